// Round 7
// baseline (268.771 us; speedup 1.0000x reference)
//
#include <hip/hip_runtime.h>
#include <cstdint>
#include <cmath>

#define DIM     256
#define NSEQ    4096
#define SCALE   0.17677669529663687f   // 32^-0.5
#define THRESH  0.6f
#define BAND    0.01f                  // recheck guard band
#define MAXSUSP 8000
#define NCHUNK  32                     // 4096 keys / 128
#define C1      0.25503483f            // SCALE * log2(e)
#define C2      28.853900818f          // 20 * log2(e)  (constant softmax shift)

using half8 = __attribute__((ext_vector_type(8))) _Float16;
using half4 = __attribute__((ext_vector_type(4))) _Float16;
using f32x4 = __attribute__((ext_vector_type(4))) float;

// ---------------------------------------------------------------------------
// Prep: coalesced LDS-tiled transpose. Wth[m][c][k] = W_m[k][c] (fp16);
// Wt[c][k] = Wq[k][c] (fp32, recheck only). Zeroes susp.
// ---------------------------------------------------------------------------
__global__ void prep_kernel(const float* __restrict__ W0, const float* __restrict__ W1,
                            const float* __restrict__ W2, const float* __restrict__ W3,
                            float* __restrict__ Wt, _Float16* __restrict__ Wth,
                            int* __restrict__ susp)
{
    __shared__ float tile[64][68];
    int t = threadIdx.x;
    int m = blockIdx.x >> 4;
    int ti = blockIdx.x & 15;
    int tr = (ti >> 2) * 64, tc = (ti & 3) * 64;
    const float* W = (m == 0) ? W0 : (m == 1) ? W1 : (m == 2) ? W2 : W3;
    if (blockIdx.x == 0 && t < 2) susp[t] = 0;
    int rr = t >> 4, c4 = (t & 15) * 4;
#pragma unroll
    for (int p = 0; p < 4; ++p) {
        int row = p * 16 + rr;
        *(float4*)&tile[row][c4] = *(const float4*)(W + (size_t)(tr + row) * DIM + tc + c4);
    }
    __syncthreads();
#pragma unroll
    for (int p = 0; p < 4; ++p) {
        int c = p * 16 + rr;
        float4 v;
        v.x = tile[c4 + 0][c]; v.y = tile[c4 + 1][c];
        v.z = tile[c4 + 2][c]; v.w = tile[c4 + 3][c];
        size_t ot = (size_t)(tc + c) * DIM + tr + c4;
        if (m == 0) *(float4*)(Wt + ot) = v;
        half4 hv;
        hv[0] = (_Float16)v.x; hv[1] = (_Float16)v.y;
        hv[2] = (_Float16)v.z; hv[3] = (_Float16)v.w;
        *(half4*)(Wth + (size_t)m * 65536 + ot) = hv;
    }
}

// ---------------------------------------------------------------------------
// Stage 1: q=x@Wq, k=y@Wk, v=x@Wv via fp16 MFMA (fp32 acc).
// ---------------------------------------------------------------------------
__global__ __launch_bounds__(256, 2)
void proj3_mfma(const float* __restrict__ x, const float* __restrict__ y,
                const _Float16* __restrict__ Wth,
                _Float16* __restrict__ qh, _Float16* __restrict__ kh,
                float* __restrict__ kf, _Float16* __restrict__ vh)
{
    __shared__ half8 sA[1024];
    __shared__ half8 sB[1024];
    int tid = threadIdx.x, w = tid >> 6, ln = tid & 63;
    int rb = blockIdx.x * 128, cb = blockIdx.y * 128, m = blockIdx.z;
    const float* A = (m == 1) ? y : x;
    const _Float16* B = Wth + (size_t)m * 65536;

    f32x4 acc[2][8];
#pragma unroll
    for (int mi = 0; mi < 2; ++mi)
#pragma unroll
        for (int nt = 0; nt < 8; ++nt) acc[mi][nt] = (f32x4){0.f, 0.f, 0.f, 0.f};

    int r = tid >> 1;
    int chalf = (tid & 1) * 4;
    for (int kc = 0; kc < 4; ++kc) {
        __syncthreads();
        const float*    asrc = A + (size_t)(rb + r) * DIM + kc * 64 + chalf * 8;
        const _Float16* bsrc = B + (size_t)(cb + r) * DIM + kc * 64 + chalf * 8;
#pragma unroll
        for (int cc = 0; cc < 4; ++cc) {
            int c = chalf + cc;
            float4 f0 = *(const float4*)(asrc + cc * 8);
            float4 f1 = *(const float4*)(asrc + cc * 8 + 4);
            half8 hv;
            hv[0] = (_Float16)f0.x; hv[1] = (_Float16)f0.y; hv[2] = (_Float16)f0.z; hv[3] = (_Float16)f0.w;
            hv[4] = (_Float16)f1.x; hv[5] = (_Float16)f1.y; hv[6] = (_Float16)f1.z; hv[7] = (_Float16)f1.w;
            int li = ((r >> 4) * 2 + (c >> 2)) * 64 + ((c & 3) << 4) + (r & 15);
            sA[li] = hv;
            sB[li] = *(const half8*)(bsrc + cc * 8);
        }
        __syncthreads();
#pragma unroll
        for (int s = 0; s < 2; ++s) {
            half8 a0 = sA[((w * 2 + 0) * 2 + s) * 64 + ln];
            half8 a1 = sA[((w * 2 + 1) * 2 + s) * 64 + ln];
#pragma unroll
            for (int nt = 0; nt < 8; ++nt) {
                half8 bv = sB[(nt * 2 + s) * 64 + ln];
                acc[0][nt] = __builtin_amdgcn_mfma_f32_16x16x32_f16(a0, bv, acc[0][nt], 0, 0, 0);
                acc[1][nt] = __builtin_amdgcn_mfma_f32_16x16x32_f16(a1, bv, acc[1][nt], 0, 0, 0);
            }
        }
    }
    int quad = ln >> 4, cix = ln & 15;
#pragma unroll
    for (int mi = 0; mi < 2; ++mi)
#pragma unroll
        for (int nt = 0; nt < 8; ++nt)
#pragma unroll
            for (int rr = 0; rr < 4; ++rr) {
                int row = rb + (w * 2 + mi) * 16 + quad * 4 + rr;
                int col = cb + nt * 16 + cix;
                size_t off = (size_t)row * DIM + col;
                float vv = acc[mi][nt][rr];
                if (m == 0)      qh[off] = (_Float16)vv;
                else if (m == 1) { kh[off] = (_Float16)vv; kf[off] = vv; }
                else             vh[off] = (_Float16)vv;
            }
}

// ---------------------------------------------------------------------------
// Stage 2: fp16 MFMA flash score pass v3.
//  - 256 q-rows/block; each wave owns 64 rows as register frags qf[4][8]
//  - grid (32 = ms + 8*b, 16 qt): XCD = g%8 = ms -> 1 MB k-set per XCD
//  - 4 k-tiles of 128 keys, 64 KB sK, 2 blocks/CU
//  - constant-shift softmax: l += exp2(a*C1 - C2); (max, argmax) by compare
// ---------------------------------------------------------------------------
__global__ __launch_bounds__(256, 2)
void flash_fp16(const _Float16* __restrict__ qh, const _Float16* __restrict__ kh,
                float* __restrict__ pm, float* __restrict__ pl, int* __restrict__ pam)
{
    __shared__ half8 sK[4096];   // 128 keys x 256 dims fp16 = 64 KB
    int tid = threadIdx.x, w = tid >> 6, ln = tid & 63;
    int g = blockIdx.x;          // ms + 8*b
    int qt = blockIdx.y;
    int ms = g & 7, b = g >> 3;
    size_t qrow0 = (size_t)b * NSEQ + qt * 256 + w * 64;
    size_t krow0 = (size_t)b * NSEQ + ms * 512;

    // one-time q fragment load (A-layout: row=ln&15, k-chunk=(ln>>4)*8)
    half8 qf[4][8];
#pragma unroll
    for (int mi = 0; mi < 4; ++mi) {
        const _Float16* qsrc = qh + (qrow0 + mi * 16 + (ln & 15)) * DIM + (ln >> 4) * 8;
#pragma unroll
        for (int ks = 0; ks < 8; ++ks)
            qf[mi][ks] = *(const half8*)(qsrc + ks * 32);
    }

    float rm[4][4], rl[4][4]; int ram[4][4];
#pragma unroll
    for (int mi = 0; mi < 4; ++mi)
#pragma unroll
        for (int rr = 0; rr < 4; ++rr) { rm[mi][rr] = -INFINITY; rl[mi][rr] = 0.f; ram[mi][rr] = 0; }

    int r = tid >> 1, h = tid & 1;
    int nt_ = r >> 4, m_ = r & 15;
    for (int kt = 0; kt < 4; ++kt) {
        __syncthreads();
        const _Float16* ksrc = kh + (krow0 + kt * 128 + r) * DIM + h * 128;
#pragma unroll
        for (int cc = 0; cc < 16; ++cc) {
            int c = h * 16 + cc;
            sK[(nt_ * 8 + (c >> 2)) * 64 + ((c & 3) << 4) + m_] = *(const half8*)(ksrc + cc * 8);
        }
        __syncthreads();

        // nt in two halves of 4 to cap acc register pressure
#pragma unroll
        for (int hf = 0; hf < 2; ++hf) {
            f32x4 acc[4][4];
#pragma unroll
            for (int mi = 0; mi < 4; ++mi)
#pragma unroll
                for (int n4 = 0; n4 < 4; ++n4) acc[mi][n4] = (f32x4){0.f, 0.f, 0.f, 0.f};

#pragma unroll
            for (int n4 = 0; n4 < 4; ++n4) {
                int nt = hf * 4 + n4;
#pragma unroll
                for (int ks = 0; ks < 8; ++ks) {
                    half8 bk = sK[(nt * 8 + ks) * 64 + ln];
                    acc[0][n4] = __builtin_amdgcn_mfma_f32_16x16x32_f16(qf[0][ks], bk, acc[0][n4], 0, 0, 0);
                    acc[1][n4] = __builtin_amdgcn_mfma_f32_16x16x32_f16(qf[1][ks], bk, acc[1][n4], 0, 0, 0);
                    acc[2][n4] = __builtin_amdgcn_mfma_f32_16x16x32_f16(qf[2][ks], bk, acc[2][n4], 0, 0, 0);
                    acc[3][n4] = __builtin_amdgcn_mfma_f32_16x16x32_f16(qf[3][ks], bk, acc[3][n4], 0, 0, 0);
                }
            }
            int keybase = b * NSEQ + ms * 512 + kt * 128 + hf * 64 + (ln & 15);
#pragma unroll
            for (int mi = 0; mi < 4; ++mi)
#pragma unroll
                for (int rr = 0; rr < 4; ++rr) {
                    float mx = rm[mi][rr]; int amx = ram[mi][rr]; float ls = rl[mi][rr];
#pragma unroll
                    for (int n4 = 0; n4 < 4; ++n4) {
                        float a = acc[mi][n4][rr];
                        ls += __builtin_amdgcn_exp2f(fmaf(a, C1, -C2));
                        if (a > mx) { mx = a; amx = keybase + n4 * 16; }
                    }
                    rm[mi][rr] = mx; ram[mi][rr] = amx; rl[mi][rr] = ls;
                }
        }
    }

    // fold the 16 key-lanes per row (xor<16 keeps quad = ln>>4): l adds, m/am max
#pragma unroll
    for (int mi = 0; mi < 4; ++mi)
#pragma unroll
        for (int rr = 0; rr < 4; ++rr) {
            float m0 = rm[mi][rr], l0 = rl[mi][rr]; int am0 = ram[mi][rr];
#pragma unroll
            for (int d = 1; d < 16; d <<= 1) {
                l0 += __shfl_xor(l0, d);
                float m2 = __shfl_xor(m0, d);
                int  am2 = __shfl_xor(am0, d);
                if (m2 > m0) { m0 = m2; am0 = am2; }
            }
            if ((ln & 15) == 0) {
                int row = b * NSEQ + qt * 256 + w * 64 + mi * 16 + (ln >> 4) * 4 + rr;
                pm[row * 8 + ms] = m0; pl[row * 8 + ms] = l0; pam[row * 8 + ms] = am0;
            }
        }
}

// ---------------------------------------------------------------------------
// Stage 2b: merge 8 ms-split partials -> (scale, idx); flag near-boundary rows.
// pm holds raw-dot max; p = exp2(m*C1 - C2) / sum(l).
// ---------------------------------------------------------------------------
__global__ void merge_kernel(const float* __restrict__ pm, const float* __restrict__ pl,
                             const int* __restrict__ pam,
                             float* __restrict__ scl, int* __restrict__ sidx,
                             int* __restrict__ susp)
{
    int row = blockIdx.x * 256 + threadIdx.x;
    float m = -INFINITY, l = 0.f; int am = 0;
#pragma unroll
    for (int s = 0; s < 8; ++s) {
        float m2 = pm[row * 8 + s];
        l += pl[row * 8 + s];
        if (m2 > m) { m = m2; am = pam[row * 8 + s]; }
    }
    float p = __builtin_amdgcn_exp2f(fmaf(m, C1, -C2)) / l;
    scl[row] = (p >= THRESH) ? p : 0.f;
    sidx[row] = am;
    if (fabsf(p - THRESH) < BAND) {
        int i = atomicAdd(susp, 1);
        if (i < MAXSUSP) susp[2 + i] = row;
    }
}

// ---------------------------------------------------------------------------
// Stage 2c-1: fp32 q-rows for suspects (Wq^T is L2-resident).
// ---------------------------------------------------------------------------
__global__ __launch_bounds__(256)
void recheck_q(const float* __restrict__ x, const float* __restrict__ Wtq,
               const int* __restrict__ susp, float* __restrict__ qsusp)
{
    int tid = threadIdx.x;
    int count = susp[0]; if (count > MAXSUSP) count = MAXSUSP;
    for (int i = blockIdx.x; i < count; i += gridDim.x) {
        int row = susp[2 + i];
        const float* xr = x + (size_t)row * DIM;
        const float* wr = Wtq + (size_t)tid * DIM;
        float a = 0.f;
        for (int d = 0; d < DIM; d += 4) {
            float4 xv = *(const float4*)(xr + d);
            float4 wv = *(const float4*)(wr + d);
            a = fmaf(xv.x, wv.x, a); a = fmaf(xv.y, wv.y, a);
            a = fmaf(xv.z, wv.z, a); a = fmaf(xv.w, wv.w, a);
        }
        qsusp[(size_t)i * DIM + tid] = a;
    }
}

// ---------------------------------------------------------------------------
// Stage 2c-2: key-parallel exact partials. Block = (chunk of 128 keys, suspect).
// ---------------------------------------------------------------------------
__global__ __launch_bounds__(256)
void recheck_part(const float* __restrict__ qsusp, const float* __restrict__ kf,
                  const int* __restrict__ susp,
                  float* __restrict__ pmP, float* __restrict__ plP, int* __restrict__ pamP)
{
    __shared__ float qs[DIM];
    __shared__ float wm[4], wl[4]; __shared__ int wa[4];
    int tid = threadIdx.x;
    int chunk = blockIdx.x;
    int count = susp[0]; if (count > MAXSUSP) count = MAXSUSP;

    for (int i = blockIdx.y; i < count; i += gridDim.y) {
        int row = susp[2 + i];
        int bb = row >> 12;
        __syncthreads();
        qs[tid] = qsusp[(size_t)i * DIM + tid];
        __syncthreads();

        int key = tid >> 1, h = tid & 1;
        int gkey = bb * NSEQ + chunk * 128 + key;
        const float* kr = kf + (size_t)gkey * DIM + h * 128;
        const float* qp = qs + h * 128;
        float dot = 0.f;
#pragma unroll
        for (int j = 0; j < 32; ++j) {
            float4 kv = *(const float4*)(kr + j * 4);
            float4 qv = *(const float4*)(qp + j * 4);
            dot = fmaf(qv.x, kv.x, dot); dot = fmaf(qv.y, kv.y, dot);
            dot = fmaf(qv.z, kv.z, dot); dot = fmaf(qv.w, kv.w, dot);
        }
        dot += __shfl_xor(dot, 1);
        float s = dot * SCALE;

        float m = (h == 0) ? s : -INFINITY;
        float l = (h == 0) ? 1.f : 0.f;
        int  am = (h == 0) ? gkey : 0;
#pragma unroll
        for (int d = 1; d < 64; d <<= 1) {
            float m2 = __shfl_xor(m, d);
            float l2 = __shfl_xor(l, d);
            int  a2 = __shfl_xor(am, d);
            if (m2 > m) { l = l * __expf(m - m2) + l2; m = m2; am = a2; }
            else        { l = l + l2 * __expf(m2 - m); }
        }
        if ((tid & 63) == 0) { wm[tid >> 6] = m; wl[tid >> 6] = l; wa[tid >> 6] = am; }
        __syncthreads();
        if (tid == 0) {
            float M = wm[0], L = wl[0]; int A = wa[0];
#pragma unroll
            for (int wv = 1; wv < 4; ++wv) {
                float m2 = wm[wv], l2 = wl[wv]; int a2 = wa[wv];
                if (m2 > M) { L = L * __expf(M - m2) + l2; M = m2; A = a2; }
                else        { L += l2 * __expf(m2 - M); }
            }
            size_t o = (size_t)i * NCHUNK + chunk;
            pmP[o] = M; plP[o] = L; pamP[o] = A;
        }
    }
}

// ---------------------------------------------------------------------------
// Stage 2c-3: fold 32 chunk-partials per suspect -> final (scale, idx).
// ---------------------------------------------------------------------------
__global__ __launch_bounds__(256)
void recheck_fold(const float* __restrict__ pmP, const float* __restrict__ plP,
                  const int* __restrict__ pamP, const int* __restrict__ susp,
                  float* __restrict__ scl, int* __restrict__ sidx)
{
    int count = susp[0]; if (count > MAXSUSP) count = MAXSUSP;
    for (int i = blockIdx.x * 256 + threadIdx.x; i < count; i += gridDim.x * 256) {
        float M = -INFINITY, L = 0.f; int A = 0;
#pragma unroll
        for (int c = 0; c < NCHUNK; ++c) {
            size_t o = (size_t)i * NCHUNK + c;
            float m2 = pmP[o], l2 = plP[o]; int a2 = pamP[o];
            if (m2 > M) { L = L * __expf(M - m2) + l2; M = m2; A = a2; }
            else        { L += l2 * __expf(m2 - M); }
        }
        float p = 1.f / L;
        int row = susp[2 + i];
        scl[row] = (p >= THRESH) ? p : 0.f;
        sidx[row] = A;
    }
}

// ---------------------------------------------------------------------------
// Stage 3: out[r] = scl[r] * (vh[idx[r]] @ Wp) + bp
// ---------------------------------------------------------------------------
__global__ __launch_bounds__(256, 2)
void out_mfma(const _Float16* __restrict__ vh, const _Float16* __restrict__ Wph,
              const float* __restrict__ scl, const int* __restrict__ sidx,
              const float* __restrict__ bp, float* __restrict__ out)
{
    __shared__ half8 sA[1024];
    __shared__ half8 sB[1024];
    int tid = threadIdx.x, w = tid >> 6, ln = tid & 63;
    int rb = blockIdx.x * 128, cb = blockIdx.y * 128;

    f32x4 acc[2][8];
#pragma unroll
    for (int mi = 0; mi < 2; ++mi)
#pragma unroll
        for (int nt = 0; nt < 8; ++nt) acc[mi][nt] = (f32x4){0.f, 0.f, 0.f, 0.f};

    int r = tid >> 1, chalf = (tid & 1) * 4;
    int gix = sidx[rb + r];
    for (int kc = 0; kc < 4; ++kc) {
        __syncthreads();
        const _Float16* asrc = vh + (size_t)gix * DIM + kc * 64 + chalf * 8;
        const _Float16* bsrc = Wph + (size_t)(cb + r) * DIM + kc * 64 + chalf * 8;
#pragma unroll
        for (int cc = 0; cc < 4; ++cc) {
            int c = chalf + cc;
            int li = ((r >> 4) * 2 + (c >> 2)) * 64 + ((c & 3) << 4) + (r & 15);
            sA[li] = *(const half8*)(asrc + cc * 8);
            sB[li] = *(const half8*)(bsrc + cc * 8);
        }
        __syncthreads();
#pragma unroll
        for (int s = 0; s < 2; ++s) {
            half8 a0 = sA[((w * 2 + 0) * 2 + s) * 64 + ln];
            half8 a1 = sA[((w * 2 + 1) * 2 + s) * 64 + ln];
#pragma unroll
            for (int nt = 0; nt < 8; ++nt) {
                half8 bv = sB[(nt * 2 + s) * 64 + ln];
                acc[0][nt] = __builtin_amdgcn_mfma_f32_16x16x32_f16(a0, bv, acc[0][nt], 0, 0, 0);
                acc[1][nt] = __builtin_amdgcn_mfma_f32_16x16x32_f16(a1, bv, acc[1][nt], 0, 0, 0);
            }
        }
    }
    int quad = ln >> 4, cix = ln & 15;
#pragma unroll
    for (int mi = 0; mi < 2; ++mi)
#pragma unroll
        for (int rr = 0; rr < 4; ++rr) {
            int row = rb + (w * 2 + mi) * 16 + quad * 4 + rr;
            float sc = scl[row];
#pragma unroll
            for (int nt = 0; nt < 8; ++nt) {
                int col = cb + nt * 16 + cix;
                out[(size_t)row * DIM + col] = acc[mi][nt][rr] * sc + bp[col];
            }
        }
}

// ---------------------------------------------------------------------------
extern "C" void kernel_launch(void* const* d_in, const int* in_sizes, int n_in,
                              void* d_out, int out_size, void* d_ws, size_t ws_size,
                              hipStream_t stream)
{
    (void)in_sizes; (void)n_in; (void)out_size; (void)ws_size;
    const float* x  = (const float*)d_in[0];
    const float* y  = (const float*)d_in[1];
    const float* Wq = (const float*)d_in[2];
    const float* Wk = (const float*)d_in[3];
    const float* Wv = (const float*)d_in[4];
    const float* Wp = (const float*)d_in[5];
    const float* bp = (const float*)d_in[6];
    float* out = (float*)d_out;

    // ws layout (~58 MB)
    float* p0 = (float*)d_ws;
    float* kf = p0;                 p0 += 4194304;
    float* Wt = p0;                 p0 += 65536;          // fp32 Wq^T (recheck)
    _Float16* Wth = (_Float16*)p0;  p0 += 4 * 65536 / 2;
    _Float16* qh  = (_Float16*)p0;  p0 += 2097152;
    _Float16* kh  = (_Float16*)p0;  p0 += 2097152;
    _Float16* vh  = (_Float16*)p0;  p0 += 2097152;
    float* pm  = p0;                p0 += 131072;
    float* pl  = p0;                p0 += 131072;
    int*  pam  = (int*)p0;          p0 += 131072;
    float* scl = p0;                p0 += 16384;
    int*  sidx = (int*)p0;          p0 += 16384;
    int*  susp = (int*)p0;          p0 += MAXSUSP + 2 + 2;
    float* qsusp = p0;              p0 += (size_t)MAXSUSP * DIM;
    float* pmP = p0;                p0 += (size_t)MAXSUSP * NCHUNK;
    float* plP = p0;                p0 += (size_t)MAXSUSP * NCHUNK;
    int*  pamP = (int*)p0;

    prep_kernel<<<64, 256, 0, stream>>>(Wq, Wk, Wv, Wp, Wt, Wth, susp);
    proj3_mfma<<<dim3(128, 2, 3), 256, 0, stream>>>(x, y, Wth, qh, kh, kf, vh);
    flash_fp16<<<dim3(32, 16), 256, 0, stream>>>(qh, kh, pm, pl, pam);
    merge_kernel<<<64, 256, 0, stream>>>(pm, pl, pam, scl, sidx, susp);
    recheck_q<<<128, 256, 0, stream>>>(x, Wt, susp, qsusp);
    recheck_part<<<dim3(NCHUNK, 64), 256, 0, stream>>>(qsusp, kf, susp, pmP, plP, pamP);
    recheck_fold<<<8, 256, 0, stream>>>(pmP, plP, pamP, susp, scl, sidx);
    out_mfma<<<dim3(128, 2), 256, 0, stream>>>(vh, Wth + 3 * 65536, scl, sidx, bp, out);
}

// Round 8
// 214.630 us; speedup vs baseline: 1.2523x; 1.2523x over previous
//
#include <hip/hip_runtime.h>
#include <cstdint>
#include <cmath>

#define DIM     256
#define NSEQ    4096
#define SCALE   0.17677669529663687f   // 32^-0.5
#define THRESH  0.6f
#define BAND    0.01f                  // recheck guard band
#define MAXSUSP 8000
#define NCHUNK  32                     // 4096 keys / 128
#define C1      0.2550349f             // SCALE * log2(e)
#define C2      28.8539008f            // 20 * log2(e)  (constant softmax shift)

using half8 = __attribute__((ext_vector_type(8))) _Float16;
using half4 = __attribute__((ext_vector_type(4))) _Float16;
using f32x4 = __attribute__((ext_vector_type(4))) float;

// async global->LDS DMA, 16 B per lane; ldst must be wave-uniform (HW adds lane*16)
__device__ __forceinline__ void async_copy16(const void* gsrc, void* ldst) {
    __builtin_amdgcn_global_load_lds(
        (const __attribute__((address_space(1))) void*)gsrc,
        (__attribute__((address_space(3))) void*)ldst, 16, 0, 0);
}

// ---------------------------------------------------------------------------
// Prep: coalesced LDS-tiled transpose. Wth[m][c][k] = W_m[k][c] (fp16);
// Wt[c][k] = Wq[k][c] (fp32, recheck only). Zeroes susp.
// ---------------------------------------------------------------------------
__global__ void prep_kernel(const float* __restrict__ W0, const float* __restrict__ W1,
                            const float* __restrict__ W2, const float* __restrict__ W3,
                            float* __restrict__ Wt, _Float16* __restrict__ Wth,
                            int* __restrict__ susp)
{
    __shared__ float tile[64][68];
    int t = threadIdx.x;
    int m = blockIdx.x >> 4;
    int ti = blockIdx.x & 15;
    int tr = (ti >> 2) * 64, tc = (ti & 3) * 64;
    const float* W = (m == 0) ? W0 : (m == 1) ? W1 : (m == 2) ? W2 : W3;
    if (blockIdx.x == 0 && t < 2) susp[t] = 0;
    int rr = t >> 4, c4 = (t & 15) * 4;
#pragma unroll
    for (int p = 0; p < 4; ++p) {
        int row = p * 16 + rr;
        *(float4*)&tile[row][c4] = *(const float4*)(W + (size_t)(tr + row) * DIM + tc + c4);
    }
    __syncthreads();
#pragma unroll
    for (int p = 0; p < 4; ++p) {
        int c = p * 16 + rr;
        float4 v;
        v.x = tile[c4 + 0][c]; v.y = tile[c4 + 1][c];
        v.z = tile[c4 + 2][c]; v.w = tile[c4 + 3][c];
        size_t ot = (size_t)(tc + c) * DIM + tr + c4;
        if (m == 0) *(float4*)(Wt + ot) = v;
        half4 hv;
        hv[0] = (_Float16)v.x; hv[1] = (_Float16)v.y;
        hv[2] = (_Float16)v.z; hv[3] = (_Float16)v.w;
        *(half4*)(Wth + (size_t)m * 65536 + ot) = hv;
    }
}

// ---------------------------------------------------------------------------
// Stage 1: q=x@Wq, k=y@Wk, v=x@Wv via fp16 MFMA (fp32 acc).
// ---------------------------------------------------------------------------
__global__ __launch_bounds__(256, 2)
void proj3_mfma(const float* __restrict__ x, const float* __restrict__ y,
                const _Float16* __restrict__ Wth,
                _Float16* __restrict__ qh, _Float16* __restrict__ kh,
                float* __restrict__ kf, _Float16* __restrict__ vh)
{
    __shared__ half8 sA[1024];
    __shared__ half8 sB[1024];
    int tid = threadIdx.x, w = tid >> 6, ln = tid & 63;
    int rb = blockIdx.x * 128, cb = blockIdx.y * 128, m = blockIdx.z;
    const float* A = (m == 1) ? y : x;
    const _Float16* B = Wth + (size_t)m * 65536;

    f32x4 acc[2][8];
#pragma unroll
    for (int mi = 0; mi < 2; ++mi)
#pragma unroll
        for (int nt = 0; nt < 8; ++nt) acc[mi][nt] = (f32x4){0.f, 0.f, 0.f, 0.f};

    int r = tid >> 1;
    int chalf = (tid & 1) * 4;
    for (int kc = 0; kc < 4; ++kc) {
        __syncthreads();
        const float*    asrc = A + (size_t)(rb + r) * DIM + kc * 64 + chalf * 8;
        const _Float16* bsrc = B + (size_t)(cb + r) * DIM + kc * 64 + chalf * 8;
#pragma unroll
        for (int cc = 0; cc < 4; ++cc) {
            int c = chalf + cc;
            float4 f0 = *(const float4*)(asrc + cc * 8);
            float4 f1 = *(const float4*)(asrc + cc * 8 + 4);
            half8 hv;
            hv[0] = (_Float16)f0.x; hv[1] = (_Float16)f0.y; hv[2] = (_Float16)f0.z; hv[3] = (_Float16)f0.w;
            hv[4] = (_Float16)f1.x; hv[5] = (_Float16)f1.y; hv[6] = (_Float16)f1.z; hv[7] = (_Float16)f1.w;
            int li = ((r >> 4) * 2 + (c >> 2)) * 64 + ((c & 3) << 4) + (r & 15);
            sA[li] = hv;
            sB[li] = *(const half8*)(bsrc + cc * 8);
        }
        __syncthreads();
#pragma unroll
        for (int s = 0; s < 2; ++s) {
            half8 a0 = sA[((w * 2 + 0) * 2 + s) * 64 + ln];
            half8 a1 = sA[((w * 2 + 1) * 2 + s) * 64 + ln];
#pragma unroll
            for (int nt = 0; nt < 8; ++nt) {
                half8 bv = sB[(nt * 2 + s) * 64 + ln];
                acc[0][nt] = __builtin_amdgcn_mfma_f32_16x16x32_f16(a0, bv, acc[0][nt], 0, 0, 0);
                acc[1][nt] = __builtin_amdgcn_mfma_f32_16x16x32_f16(a1, bv, acc[1][nt], 0, 0, 0);
            }
        }
    }
    int quad = ln >> 4, cix = ln & 15;
#pragma unroll
    for (int mi = 0; mi < 2; ++mi)
#pragma unroll
        for (int nt = 0; nt < 8; ++nt)
#pragma unroll
            for (int rr = 0; rr < 4; ++rr) {
                int row = rb + (w * 2 + mi) * 16 + quad * 4 + rr;
                int col = cb + nt * 16 + cix;
                size_t off = (size_t)row * DIM + col;
                float vv = acc[mi][nt][rr];
                if (m == 0)      qh[off] = (_Float16)vv;
                else if (m == 1) { kh[off] = (_Float16)vv; kf[off] = vv; }
                else             vh[off] = (_Float16)vv;
            }
}

// ---------------------------------------------------------------------------
// Stage 2: fp16 MFMA flash score pass (R6 structure = known 62 us baseline):
//  - 128 q-rows/block, wave owns 32 rows as register frags qf[2][8] (NO mi=4:
//    R7 showed 128-reg qf spills -> 150 MB scratch writes. Do not repeat.)
//  - grid (16 = ms+4b, 32 qt); 8 k-tiles of 128 keys; 64 KB sK; 2 blocks/CU
//  NEW vs R6:
//  - staging via global_load_lds 16B DMA (frag-major sK groups are exactly
//    wave-uniform-base + lane*16) -> no staging VGPRs/VALU
//  - constant-shift softmax: l += exp2(a*C1 - C2); max/argmax by compare only
// ---------------------------------------------------------------------------
__global__ __launch_bounds__(256, 2)
void flash_fp16(const _Float16* __restrict__ qh, const _Float16* __restrict__ kh,
                float* __restrict__ pm, float* __restrict__ pl, int* __restrict__ pam)
{
    __shared__ half8 sK[4096];   // 128 keys x 256 dims fp16 = 64 KB
    int tid = threadIdx.x, w = tid >> 6, ln = tid & 63;
    int g = blockIdx.x;          // ms + 4*b
    int qt = blockIdx.y;
    int ms = g & 3, b = g >> 2;
    size_t qbase = (size_t)b * NSEQ + qt * 128 + w * 32;
    size_t krow0 = (size_t)b * NSEQ + ms * 1024;
    int ln15 = ln & 15, ln4 = ln >> 4;

    // one-time q fragment load (A-layout: row=ln&15, k-chunk=(ln>>4)*8)
    half8 qf[2][8];
#pragma unroll
    for (int mi = 0; mi < 2; ++mi) {
        const _Float16* qsrc = qh + (qbase + mi * 16 + ln15) * DIM + ln4 * 8;
#pragma unroll
        for (int ks = 0; ks < 8; ++ks)
            qf[mi][ks] = *(const half8*)(qsrc + ks * 32);
    }

    float rm[2][4], rl[2][4]; int ram[2][4];
#pragma unroll
    for (int mi = 0; mi < 2; ++mi)
#pragma unroll
        for (int rr = 0; rr < 4; ++rr) { rm[mi][rr] = -INFINITY; rl[mi][rr] = 0.f; ram[mi][rr] = 0; }

    for (int kt = 0; kt < 8; ++kt) {
        __syncthreads();   // previous tile's frag reads complete
        // async DMA staging: wave w fills groups w*16..w*16+15 (1 KB each).
        // group grp=(nt*8+ks): lane ln -> B[n=ln&15][k=(ln>>4)*8..+8] of k-step ks.
#pragma unroll
        for (int j = 0; j < 16; ++j) {
            int grp = w * 16 + j;
            int nt = grp >> 3, ks = grp & 7;
            const _Float16* src = kh + (krow0 + kt * 128 + nt * 16 + ln15) * DIM + ks * 32 + ln4 * 8;
            async_copy16(src, (char*)sK + grp * 1024);
        }
        __syncthreads();   // drains vmcnt -> sK ready

        f32x4 acc[2][8];
#pragma unroll
        for (int mi = 0; mi < 2; ++mi)
#pragma unroll
            for (int nt = 0; nt < 8; ++nt) acc[mi][nt] = (f32x4){0.f, 0.f, 0.f, 0.f};

#pragma unroll
        for (int nt = 0; nt < 8; ++nt)
#pragma unroll
            for (int ks = 0; ks < 8; ++ks) {
                half8 bk = sK[(nt * 8 + ks) * 64 + ln];
                acc[0][nt] = __builtin_amdgcn_mfma_f32_16x16x32_f16(qf[0][ks], bk, acc[0][nt], 0, 0, 0);
                acc[1][nt] = __builtin_amdgcn_mfma_f32_16x16x32_f16(qf[1][ks], bk, acc[1][nt], 0, 0, 0);
            }

        int keybase = b * NSEQ + ms * 1024 + kt * 128 + ln15;
#pragma unroll
        for (int mi = 0; mi < 2; ++mi)
#pragma unroll
            for (int rr = 0; rr < 4; ++rr) {
                float mx = rm[mi][rr]; int amx = ram[mi][rr]; float ls = rl[mi][rr];
#pragma unroll
                for (int nt = 0; nt < 8; ++nt) {
                    float a = acc[mi][nt][rr];
                    ls += __builtin_amdgcn_exp2f(fmaf(a, C1, -C2));
                    if (a > mx) { mx = a; amx = keybase + nt * 16; }
                }
                rm[mi][rr] = mx; ram[mi][rr] = amx; rl[mi][rr] = ls;
            }
    }

    // fold the 16 key-lanes per row (xor<16 keeps quad = ln>>4): l adds, m/am max
#pragma unroll
    for (int mi = 0; mi < 2; ++mi)
#pragma unroll
        for (int rr = 0; rr < 4; ++rr) {
            float m0 = rm[mi][rr], l0 = rl[mi][rr]; int am0 = ram[mi][rr];
#pragma unroll
            for (int d = 1; d < 16; d <<= 1) {
                l0 += __shfl_xor(l0, d);
                float m2 = __shfl_xor(m0, d);
                int  am2 = __shfl_xor(am0, d);
                if (m2 > m0) { m0 = m2; am0 = am2; }
            }
            if (ln15 == 0) {
                int row = b * NSEQ + qt * 128 + w * 32 + mi * 16 + ln4 * 4 + rr;
                pm[row * 4 + ms] = m0; pl[row * 4 + ms] = l0; pam[row * 4 + ms] = am0;
            }
        }
}

// ---------------------------------------------------------------------------
// Stage 2b: merge 4 ms-split partials -> (scale, idx); flag near-boundary rows.
// pm holds raw-dot max; p = exp2(m*C1 - C2) / sum(l)  (shift cancels exactly).
// ---------------------------------------------------------------------------
__global__ void merge_kernel(const float* __restrict__ pm, const float* __restrict__ pl,
                             const int* __restrict__ pam,
                             float* __restrict__ scl, int* __restrict__ sidx,
                             int* __restrict__ susp)
{
    int row = blockIdx.x * 256 + threadIdx.x;
    float m = -INFINITY, l = 0.f; int am = 0;
#pragma unroll
    for (int s = 0; s < 4; ++s) {
        float m2 = pm[row * 4 + s];
        l += pl[row * 4 + s];
        if (m2 > m) { m = m2; am = pam[row * 4 + s]; }
    }
    float p = __builtin_amdgcn_exp2f(fmaf(m, C1, -C2)) / l;
    scl[row] = (p >= THRESH) ? p : 0.f;
    sidx[row] = am;
    if (fabsf(p - THRESH) < BAND) {
        int i = atomicAdd(susp, 1);
        if (i < MAXSUSP) susp[2 + i] = row;
    }
}

// ---------------------------------------------------------------------------
// Stage 2c-1: fp32 q-rows for suspects (Wq^T is L2-resident).
// ---------------------------------------------------------------------------
__global__ __launch_bounds__(256)
void recheck_q(const float* __restrict__ x, const float* __restrict__ Wtq,
               const int* __restrict__ susp, float* __restrict__ qsusp)
{
    int tid = threadIdx.x;
    int count = susp[0]; if (count > MAXSUSP) count = MAXSUSP;
    for (int i = blockIdx.x; i < count; i += gridDim.x) {
        int row = susp[2 + i];
        const float* xr = x + (size_t)row * DIM;
        const float* wr = Wtq + (size_t)tid * DIM;
        float a = 0.f;
        for (int d = 0; d < DIM; d += 4) {
            float4 xv = *(const float4*)(xr + d);
            float4 wv = *(const float4*)(wr + d);
            a = fmaf(xv.x, wv.x, a); a = fmaf(xv.y, wv.y, a);
            a = fmaf(xv.z, wv.z, a); a = fmaf(xv.w, wv.w, a);
        }
        qsusp[(size_t)i * DIM + tid] = a;
    }
}

// ---------------------------------------------------------------------------
// Stage 2c-2: key-parallel exact partials. Block = (chunk of 128 keys, suspect).
// ---------------------------------------------------------------------------
__global__ __launch_bounds__(256)
void recheck_part(const float* __restrict__ qsusp, const float* __restrict__ kf,
                  const int* __restrict__ susp,
                  float* __restrict__ pmP, float* __restrict__ plP, int* __restrict__ pamP)
{
    __shared__ float qs[DIM];
    __shared__ float wm[4], wl[4]; __shared__ int wa[4];
    int tid = threadIdx.x;
    int chunk = blockIdx.x;
    int count = susp[0]; if (count > MAXSUSP) count = MAXSUSP;

    for (int i = blockIdx.y; i < count; i += gridDim.y) {
        int row = susp[2 + i];
        int bb = row >> 12;
        __syncthreads();
        qs[tid] = qsusp[(size_t)i * DIM + tid];
        __syncthreads();

        int key = tid >> 1, h = tid & 1;
        int gkey = bb * NSEQ + chunk * 128 + key;
        const float* kr = kf + (size_t)gkey * DIM + h * 128;
        const float* qp = qs + h * 128;
        float dot = 0.f;
#pragma unroll
        for (int j = 0; j < 32; ++j) {
            float4 kv = *(const float4*)(kr + j * 4);
            float4 qv = *(const float4*)(qp + j * 4);
            dot = fmaf(qv.x, kv.x, dot); dot = fmaf(qv.y, kv.y, dot);
            dot = fmaf(qv.z, kv.z, dot); dot = fmaf(qv.w, kv.w, dot);
        }
        dot += __shfl_xor(dot, 1);
        float s = dot * SCALE;

        float m = (h == 0) ? s : -INFINITY;
        float l = (h == 0) ? 1.f : 0.f;
        int  am = (h == 0) ? gkey : 0;
#pragma unroll
        for (int d = 1; d < 64; d <<= 1) {
            float m2 = __shfl_xor(m, d);
            float l2 = __shfl_xor(l, d);
            int  a2 = __shfl_xor(am, d);
            if (m2 > m) { l = l * __expf(m - m2) + l2; m = m2; am = a2; }
            else        { l = l + l2 * __expf(m2 - m); }
        }
        if ((tid & 63) == 0) { wm[tid >> 6] = m; wl[tid >> 6] = l; wa[tid >> 6] = am; }
        __syncthreads();
        if (tid == 0) {
            float M = wm[0], L = wl[0]; int A = wa[0];
#pragma unroll
            for (int wv = 1; wv < 4; ++wv) {
                float m2 = wm[wv], l2 = wl[wv]; int a2 = wa[wv];
                if (m2 > M) { L = L * __expf(M - m2) + l2; M = m2; A = a2; }
                else        { L += l2 * __expf(m2 - M); }
            }
            size_t o = (size_t)i * NCHUNK + chunk;
            pmP[o] = M; plP[o] = L; pamP[o] = A;
        }
    }
}

// ---------------------------------------------------------------------------
// Stage 2c-3: fold 32 chunk-partials per suspect -> final (scale, idx).
// ---------------------------------------------------------------------------
__global__ __launch_bounds__(256)
void recheck_fold(const float* __restrict__ pmP, const float* __restrict__ plP,
                  const int* __restrict__ pamP, const int* __restrict__ susp,
                  float* __restrict__ scl, int* __restrict__ sidx)
{
    int count = susp[0]; if (count > MAXSUSP) count = MAXSUSP;
    for (int i = blockIdx.x * 256 + threadIdx.x; i < count; i += gridDim.x * 256) {
        float M = -INFINITY, L = 0.f; int A = 0;
#pragma unroll
        for (int c = 0; c < NCHUNK; ++c) {
            size_t o = (size_t)i * NCHUNK + c;
            float m2 = pmP[o], l2 = plP[o]; int a2 = pamP[o];
            if (m2 > M) { L = L * __expf(M - m2) + l2; M = m2; A = a2; }
            else        { L += l2 * __expf(m2 - M); }
        }
        float p = 1.f / L;
        int row = susp[2 + i];
        scl[row] = (p >= THRESH) ? p : 0.f;
        sidx[row] = A;
    }
}

// ---------------------------------------------------------------------------
// Stage 3: out[r] = scl[r] * (vh[idx[r]] @ Wp) + bp
// ---------------------------------------------------------------------------
__global__ __launch_bounds__(256, 2)
void out_mfma(const _Float16* __restrict__ vh, const _Float16* __restrict__ Wph,
              const float* __restrict__ scl, const int* __restrict__ sidx,
              const float* __restrict__ bp, float* __restrict__ out)
{
    __shared__ half8 sA[1024];
    __shared__ half8 sB[1024];
    int tid = threadIdx.x, w = tid >> 6, ln = tid & 63;
    int rb = blockIdx.x * 128, cb = blockIdx.y * 128;

    f32x4 acc[2][8];
#pragma unroll
    for (int mi = 0; mi < 2; ++mi)
#pragma unroll
        for (int nt = 0; nt < 8; ++nt) acc[mi][nt] = (f32x4){0.f, 0.f, 0.f, 0.f};

    int r = tid >> 1, chalf = (tid & 1) * 4;
    int gix = sidx[rb + r];
    for (int kc = 0; kc < 4; ++kc) {
        __syncthreads();
        const _Float16* asrc = vh + (size_t)gix * DIM + kc * 64 + chalf * 8;
        const _Float16* bsrc = Wph + (size_t)(cb + r) * DIM + kc * 64 + chalf * 8;
#pragma unroll
        for (int cc = 0; cc < 4; ++cc) {
            int c = chalf + cc;
            int li = ((r >> 4) * 2 + (c >> 2)) * 64 + ((c & 3) << 4) + (r & 15);
            sA[li] = *(const half8*)(asrc + cc * 8);
            sB[li] = *(const half8*)(bsrc + cc * 8);
        }
        __syncthreads();
#pragma unroll
        for (int s = 0; s < 2; ++s) {
            half8 a0 = sA[((w * 2 + 0) * 2 + s) * 64 + ln];
            half8 a1 = sA[((w * 2 + 1) * 2 + s) * 64 + ln];
#pragma unroll
            for (int nt = 0; nt < 8; ++nt) {
                half8 bv = sB[(nt * 2 + s) * 64 + ln];
                acc[0][nt] = __builtin_amdgcn_mfma_f32_16x16x32_f16(a0, bv, acc[0][nt], 0, 0, 0);
                acc[1][nt] = __builtin_amdgcn_mfma_f32_16x16x32_f16(a1, bv, acc[1][nt], 0, 0, 0);
            }
        }
    }
    int quad = ln >> 4, cix = ln & 15;
#pragma unroll
    for (int mi = 0; mi < 2; ++mi)
#pragma unroll
        for (int rr = 0; rr < 4; ++rr) {
            int row = rb + (w * 2 + mi) * 16 + quad * 4 + rr;
            float sc = scl[row];
#pragma unroll
            for (int nt = 0; nt < 8; ++nt) {
                int col = cb + nt * 16 + cix;
                out[(size_t)row * DIM + col] = acc[mi][nt][rr] * sc + bp[col];
            }
        }
}

// ---------------------------------------------------------------------------
extern "C" void kernel_launch(void* const* d_in, const int* in_sizes, int n_in,
                              void* d_out, int out_size, void* d_ws, size_t ws_size,
                              hipStream_t stream)
{
    (void)in_sizes; (void)n_in; (void)out_size; (void)ws_size;
    const float* x  = (const float*)d_in[0];
    const float* y  = (const float*)d_in[1];
    const float* Wq = (const float*)d_in[2];
    const float* Wk = (const float*)d_in[3];
    const float* Wv = (const float*)d_in[4];
    const float* Wp = (const float*)d_in[5];
    const float* bp = (const float*)d_in[6];
    float* out = (float*)d_out;

    // ws layout (~56 MB)
    float* p0 = (float*)d_ws;
    float* kf = p0;                 p0 += 4194304;
    float* Wt = p0;                 p0 += 65536;          // fp32 Wq^T (recheck)
    _Float16* Wth = (_Float16*)p0;  p0 += 4 * 65536 / 2;
    _Float16* qh  = (_Float16*)p0;  p0 += 2097152;
    _Float16* kh  = (_Float16*)p0;  p0 += 2097152;
    _Float16* vh  = (_Float16*)p0;  p0 += 2097152;
    float* pm  = p0;                p0 += 65536;
    float* pl  = p0;                p0 += 65536;
    int*  pam  = (int*)p0;          p0 += 65536;
    float* scl = p0;                p0 += 16384;
    int*  sidx = (int*)p0;          p0 += 16384;
    int*  susp = (int*)p0;          p0 += MAXSUSP + 2 + 2;
    float* qsusp = p0;              p0 += (size_t)MAXSUSP * DIM;
    float* pmP = p0;                p0 += (size_t)MAXSUSP * NCHUNK;
    float* plP = p0;                p0 += (size_t)MAXSUSP * NCHUNK;
    int*  pamP = (int*)p0;

    prep_kernel<<<64, 256, 0, stream>>>(Wq, Wk, Wv, Wp, Wt, Wth, susp);
    proj3_mfma<<<dim3(128, 2, 3), 256, 0, stream>>>(x, y, Wth, qh, kh, kf, vh);
    flash_fp16<<<dim3(16, 32), 256, 0, stream>>>(qh, kh, pm, pl, pam);
    merge_kernel<<<64, 256, 0, stream>>>(pm, pl, pam, scl, sidx, susp);
    recheck_q<<<128, 256, 0, stream>>>(x, Wt, susp, qsusp);
    recheck_part<<<dim3(NCHUNK, 64), 256, 0, stream>>>(qsusp, kf, susp, pmP, plP, pamP);
    recheck_fold<<<8, 256, 0, stream>>>(pmP, plP, pamP, susp, scl, sidx);
    out_mfma<<<dim3(128, 2), 256, 0, stream>>>(vh, Wth + 3 * 65536, scl, sidx, bp, out);
}

// Round 9
// 210.845 us; speedup vs baseline: 1.2747x; 1.0180x over previous
//
#include <hip/hip_runtime.h>
#include <cstdint>
#include <cmath>

#define DIM     256
#define NSEQ    4096
#define SCALE   0.17677669529663687f   // 32^-0.5
#define THRESH  0.6f
#define BAND    0.01f                  // recheck guard band
#define MAXSUSP 8000
#define NCHUNK  32                     // 4096 keys / 128
#define C1      0.2550349f             // SCALE * log2(e)
#define C2      28.8539008f            // 20 * log2(e)  (constant softmax shift)

using half8 = __attribute__((ext_vector_type(8))) _Float16;
using half4 = __attribute__((ext_vector_type(4))) _Float16;
using f32x4 = __attribute__((ext_vector_type(4))) float;

// async global->LDS DMA, 16 B per lane; ldst must be wave-uniform (HW adds lane*16)
__device__ __forceinline__ void async_copy16(const void* gsrc, void* ldst) {
    __builtin_amdgcn_global_load_lds(
        (const __attribute__((address_space(1))) void*)gsrc,
        (__attribute__((address_space(3))) void*)ldst, 16, 0, 0);
}

// fp32x8 -> half8 (A-fragment inline conversion)
__device__ __forceinline__ half8 cvt8(const float* p) {
    float4 f0 = *(const float4*)p;
    float4 f1 = *(const float4*)(p + 4);
    half8 hv;
    hv[0] = (_Float16)f0.x; hv[1] = (_Float16)f0.y; hv[2] = (_Float16)f0.z; hv[3] = (_Float16)f0.w;
    hv[4] = (_Float16)f1.x; hv[5] = (_Float16)f1.y; hv[6] = (_Float16)f1.z; hv[7] = (_Float16)f1.w;
    return hv;
}

// ---------------------------------------------------------------------------
// Prep: coalesced LDS-tiled transpose. Wth[m][c][k] = W_m[k][c] (fp16);
// Wt[c][k] = Wq[k][c] (fp32, recheck only). Zeroes susp.
// ---------------------------------------------------------------------------
__global__ void prep_kernel(const float* __restrict__ W0, const float* __restrict__ W1,
                            const float* __restrict__ W2, const float* __restrict__ W3,
                            float* __restrict__ Wt, _Float16* __restrict__ Wth,
                            int* __restrict__ susp)
{
    __shared__ float tile[64][68];
    int t = threadIdx.x;
    int m = blockIdx.x >> 4;
    int ti = blockIdx.x & 15;
    int tr = (ti >> 2) * 64, tc = (ti & 3) * 64;
    const float* W = (m == 0) ? W0 : (m == 1) ? W1 : (m == 2) ? W2 : W3;
    if (blockIdx.x == 0 && t < 2) susp[t] = 0;
    int rr = t >> 4, c4 = (t & 15) * 4;
#pragma unroll
    for (int p = 0; p < 4; ++p) {
        int row = p * 16 + rr;
        *(float4*)&tile[row][c4] = *(const float4*)(W + (size_t)(tr + row) * DIM + tc + c4);
    }
    __syncthreads();
#pragma unroll
    for (int p = 0; p < 4; ++p) {
        int c = p * 16 + rr;
        float4 v;
        v.x = tile[c4 + 0][c]; v.y = tile[c4 + 1][c];
        v.z = tile[c4 + 2][c]; v.w = tile[c4 + 3][c];
        size_t ot = (size_t)(tc + c) * DIM + tr + c4;
        if (m == 0) *(float4*)(Wt + ot) = v;
        half4 hv;
        hv[0] = (_Float16)v.x; hv[1] = (_Float16)v.y;
        hv[2] = (_Float16)v.z; hv[3] = (_Float16)v.w;
        *(half4*)(Wth + (size_t)m * 65536 + ot) = hv;
    }
}

// ---------------------------------------------------------------------------
// Stage 1 v2: q=x@Wq, k=y@Wk, v=x@Wv. Single-barrier structure:
//  - 64 KB weight half-tile (128 cols x 256 k) DMA'd to LDS frag-major ONCE
//  - A rows (x/y, fp32) loaded straight into A-layout register frags + cvt
//  - 128 MFMAs, zero k-loop barriers
// ---------------------------------------------------------------------------
__global__ __launch_bounds__(256, 2)
void proj3_mfma(const float* __restrict__ x, const float* __restrict__ y,
                const _Float16* __restrict__ Wth,
                _Float16* __restrict__ qh, _Float16* __restrict__ kh,
                float* __restrict__ kf, _Float16* __restrict__ vh)
{
    __shared__ half8 sB[4096];   // 128 cols x 256 k fp16 = 64 KB, grp = nt*8+ks
    int tid = threadIdx.x, w = tid >> 6, ln = tid & 63;
    int ln15 = ln & 15, ln4 = ln >> 4;
    int rb = blockIdx.x * 128, cbh = blockIdx.y, m = blockIdx.z;
    const float* A = (m == 1) ? y : x;
    const _Float16* B = Wth + (size_t)m * 65536 + (size_t)cbh * 128 * DIM;

    // DMA the whole B half-tile: 64 groups of 1 KB; wave w issues 16
#pragma unroll
    for (int j = 0; j < 16; ++j) {
        int grp = w * 16 + j;
        int nt = grp >> 3, ks = grp & 7;
        const _Float16* src = B + (size_t)(nt * 16 + ln15) * DIM + ks * 32 + ln4 * 8;
        async_copy16(src, (char*)sB + grp * 1024);
    }

    // A fragments (proven qf pattern: row=ln&15, k-chunk=(ln>>4)*8) + fp32->fp16
    half8 af[2][8];
#pragma unroll
    for (int mi = 0; mi < 2; ++mi) {
        const float* ar = A + (size_t)(rb + w * 32 + mi * 16 + ln15) * DIM + ln4 * 8;
#pragma unroll
        for (int ks = 0; ks < 8; ++ks)
            af[mi][ks] = cvt8(ar + ks * 32);
    }

    __syncthreads();   // drains B DMA

    f32x4 acc[2][8];
#pragma unroll
    for (int mi = 0; mi < 2; ++mi)
#pragma unroll
        for (int nt = 0; nt < 8; ++nt) acc[mi][nt] = (f32x4){0.f, 0.f, 0.f, 0.f};

#pragma unroll
    for (int nt = 0; nt < 8; ++nt)
#pragma unroll
        for (int ks = 0; ks < 8; ++ks) {
            half8 bv = sB[(nt * 8 + ks) * 64 + ln];
            acc[0][nt] = __builtin_amdgcn_mfma_f32_16x16x32_f16(af[0][ks], bv, acc[0][nt], 0, 0, 0);
            acc[1][nt] = __builtin_amdgcn_mfma_f32_16x16x32_f16(af[1][ks], bv, acc[1][nt], 0, 0, 0);
        }

    int quad = ln4, cix = ln15;
#pragma unroll
    for (int mi = 0; mi < 2; ++mi)
#pragma unroll
        for (int nt = 0; nt < 8; ++nt)
#pragma unroll
            for (int rr = 0; rr < 4; ++rr) {
                int row = rb + (w * 2 + mi) * 16 + quad * 4 + rr;
                int col = cbh * 128 + nt * 16 + cix;
                size_t off = (size_t)row * DIM + col;
                float vv = acc[mi][nt][rr];
                if (m == 0)      qh[off] = (_Float16)vv;
                else if (m == 1) { kh[off] = (_Float16)vv; kf[off] = vv; }
                else             vh[off] = (_Float16)vv;
            }
}

// ---------------------------------------------------------------------------
// Stage 2: fp16 MFMA flash score pass, double-buffered prefetch:
//  - 16 k-tiles of 64 keys; 2 x 32 KB LDS buffers; ONE barrier per tile,
//    DMA for tile t+1 issued right after the barrier -> drain is free
//  - q frags in registers (qf[2][8]; mi=4 spills, R7)
//  - constant-shift softmax: l += exp2(a*C1 - C2); max/argmax by compare
// ---------------------------------------------------------------------------
__global__ __launch_bounds__(256, 2)
void flash_fp16(const _Float16* __restrict__ qh, const _Float16* __restrict__ kh,
                float* __restrict__ pm, float* __restrict__ pl, int* __restrict__ pam)
{
    __shared__ half8 sK[2][2048];   // 2 x (64 keys x 256 dims) = 2 x 32 KB
    int tid = threadIdx.x, w = tid >> 6, ln = tid & 63;
    int g = blockIdx.x;          // ms + 4*b
    int qt = blockIdx.y;
    int ms = g & 3, b = g >> 2;
    size_t qbase = (size_t)b * NSEQ + qt * 128 + w * 32;
    size_t krow0 = (size_t)b * NSEQ + ms * 1024;
    int ln15 = ln & 15, ln4 = ln >> 4;

    half8 qf[2][8];
#pragma unroll
    for (int mi = 0; mi < 2; ++mi) {
        const _Float16* qsrc = qh + (qbase + mi * 16 + ln15) * DIM + ln4 * 8;
#pragma unroll
        for (int ks = 0; ks < 8; ++ks)
            qf[mi][ks] = *(const half8*)(qsrc + ks * 32);
    }

    float rm[2][4], rl[2][4]; int ram[2][4];
#pragma unroll
    for (int mi = 0; mi < 2; ++mi)
#pragma unroll
        for (int rr = 0; rr < 4; ++rr) { rm[mi][rr] = -INFINITY; rl[mi][rr] = 0.f; ram[mi][rr] = 0; }

    // prologue: prefetch tile 0 into buffer 0 (32 groups of 1 KB; wave w: 8)
#pragma unroll
    for (int j = 0; j < 8; ++j) {
        int grp = w * 8 + j;
        const _Float16* src = kh + (krow0 + (grp >> 3) * 16 + ln15) * DIM + (grp & 7) * 32 + ln4 * 8;
        async_copy16(src, (char*)&sK[0][0] + grp * 1024);
    }

    for (int kt = 0; kt < 16; ++kt) {
        int cur = kt & 1;
        __syncthreads();   // tile kt's DMA complete; prior reads of buf[1-cur] done

        if (kt + 1 < 16) {
#pragma unroll
            for (int j = 0; j < 8; ++j) {
                int grp = w * 8 + j;
                const _Float16* src = kh + (krow0 + (kt + 1) * 64 + (grp >> 3) * 16 + ln15) * DIM
                                      + (grp & 7) * 32 + ln4 * 8;
                async_copy16(src, (char*)&sK[1 - cur][0] + grp * 1024);
            }
        }

        const half8* sKc = &sK[cur][0];
        f32x4 acc[2][4];
#pragma unroll
        for (int mi = 0; mi < 2; ++mi)
#pragma unroll
            for (int nt = 0; nt < 4; ++nt) acc[mi][nt] = (f32x4){0.f, 0.f, 0.f, 0.f};

#pragma unroll
        for (int nt = 0; nt < 4; ++nt)
#pragma unroll
            for (int ks = 0; ks < 8; ++ks) {
                half8 bk = sKc[(nt * 8 + ks) * 64 + ln];
                acc[0][nt] = __builtin_amdgcn_mfma_f32_16x16x32_f16(qf[0][ks], bk, acc[0][nt], 0, 0, 0);
                acc[1][nt] = __builtin_amdgcn_mfma_f32_16x16x32_f16(qf[1][ks], bk, acc[1][nt], 0, 0, 0);
            }

        int keybase = b * NSEQ + ms * 1024 + kt * 64 + ln15;
#pragma unroll
        for (int mi = 0; mi < 2; ++mi)
#pragma unroll
            for (int rr = 0; rr < 4; ++rr) {
                float mx = rm[mi][rr]; int amx = ram[mi][rr]; float ls = rl[mi][rr];
#pragma unroll
                for (int nt = 0; nt < 4; ++nt) {
                    float a = acc[mi][nt][rr];
                    ls += __builtin_amdgcn_exp2f(fmaf(a, C1, -C2));
                    if (a > mx) { mx = a; amx = keybase + nt * 16; }
                }
                rm[mi][rr] = mx; ram[mi][rr] = amx; rl[mi][rr] = ls;
            }
    }

    // fold the 16 key-lanes per row (xor<16 keeps quad = ln>>4): l adds, m/am max
#pragma unroll
    for (int mi = 0; mi < 2; ++mi)
#pragma unroll
        for (int rr = 0; rr < 4; ++rr) {
            float m0 = rm[mi][rr], l0 = rl[mi][rr]; int am0 = ram[mi][rr];
#pragma unroll
            for (int d = 1; d < 16; d <<= 1) {
                l0 += __shfl_xor(l0, d);
                float m2 = __shfl_xor(m0, d);
                int  am2 = __shfl_xor(am0, d);
                if (m2 > m0) { m0 = m2; am0 = am2; }
            }
            if (ln15 == 0) {
                int row = b * NSEQ + qt * 128 + w * 32 + mi * 16 + ln4 * 4 + rr;
                pm[row * 4 + ms] = m0; pl[row * 4 + ms] = l0; pam[row * 4 + ms] = am0;
            }
        }
}

// ---------------------------------------------------------------------------
// Stage 2b: merge 4 ms-split partials -> (scale, idx); flag near-boundary rows.
// pm holds raw-dot max; p = exp2(m*C1 - C2) / sum(l)  (shift cancels exactly).
// ---------------------------------------------------------------------------
__global__ void merge_kernel(const float* __restrict__ pm, const float* __restrict__ pl,
                             const int* __restrict__ pam,
                             float* __restrict__ scl, int* __restrict__ sidx,
                             int* __restrict__ susp)
{
    int row = blockIdx.x * 256 + threadIdx.x;
    float m = -INFINITY, l = 0.f; int am = 0;
#pragma unroll
    for (int s = 0; s < 4; ++s) {
        float m2 = pm[row * 4 + s];
        l += pl[row * 4 + s];
        if (m2 > m) { m = m2; am = pam[row * 4 + s]; }
    }
    float p = __builtin_amdgcn_exp2f(fmaf(m, C1, -C2)) / l;
    scl[row] = (p >= THRESH) ? p : 0.f;
    sidx[row] = am;
    if (fabsf(p - THRESH) < BAND) {
        int i = atomicAdd(susp, 1);
        if (i < MAXSUSP) susp[2 + i] = row;
    }
}

// ---------------------------------------------------------------------------
// Stage 2c-1: fp32 q-rows for suspects (Wq^T is L2-resident).
// ---------------------------------------------------------------------------
__global__ __launch_bounds__(256)
void recheck_q(const float* __restrict__ x, const float* __restrict__ Wtq,
               const int* __restrict__ susp, float* __restrict__ qsusp)
{
    int tid = threadIdx.x;
    int count = susp[0]; if (count > MAXSUSP) count = MAXSUSP;
    for (int i = blockIdx.x; i < count; i += gridDim.x) {
        int row = susp[2 + i];
        const float* xr = x + (size_t)row * DIM;
        const float* wr = Wtq + (size_t)tid * DIM;
        float a = 0.f;
        for (int d = 0; d < DIM; d += 4) {
            float4 xv = *(const float4*)(xr + d);
            float4 wv = *(const float4*)(wr + d);
            a = fmaf(xv.x, wv.x, a); a = fmaf(xv.y, wv.y, a);
            a = fmaf(xv.z, wv.z, a); a = fmaf(xv.w, wv.w, a);
        }
        qsusp[(size_t)i * DIM + tid] = a;
    }
}

// ---------------------------------------------------------------------------
// Stage 2c-2: key-parallel exact partials. Block = (chunk of 128 keys, suspect).
// ---------------------------------------------------------------------------
__global__ __launch_bounds__(256)
void recheck_part(const float* __restrict__ qsusp, const float* __restrict__ kf,
                  const int* __restrict__ susp,
                  float* __restrict__ pmP, float* __restrict__ plP, int* __restrict__ pamP)
{
    __shared__ float qs[DIM];
    __shared__ float wm[4], wl[4]; __shared__ int wa[4];
    int tid = threadIdx.x;
    int chunk = blockIdx.x;
    int count = susp[0]; if (count > MAXSUSP) count = MAXSUSP;

    for (int i = blockIdx.y; i < count; i += gridDim.y) {
        int row = susp[2 + i];
        int bb = row >> 12;
        __syncthreads();
        qs[tid] = qsusp[(size_t)i * DIM + tid];
        __syncthreads();

        int key = tid >> 1, h = tid & 1;
        int gkey = bb * NSEQ + chunk * 128 + key;
        const float* kr = kf + (size_t)gkey * DIM + h * 128;
        const float* qp = qs + h * 128;
        float dot = 0.f;
#pragma unroll
        for (int j = 0; j < 32; ++j) {
            float4 kv = *(const float4*)(kr + j * 4);
            float4 qv = *(const float4*)(qp + j * 4);
            dot = fmaf(qv.x, kv.x, dot); dot = fmaf(qv.y, kv.y, dot);
            dot = fmaf(qv.z, kv.z, dot); dot = fmaf(qv.w, kv.w, dot);
        }
        dot += __shfl_xor(dot, 1);
        float s = dot * SCALE;

        float m = (h == 0) ? s : -INFINITY;
        float l = (h == 0) ? 1.f : 0.f;
        int  am = (h == 0) ? gkey : 0;
#pragma unroll
        for (int d = 1; d < 64; d <<= 1) {
            float m2 = __shfl_xor(m, d);
            float l2 = __shfl_xor(l, d);
            int  a2 = __shfl_xor(am, d);
            if (m2 > m) { l = l * __expf(m - m2) + l2; m = m2; am = a2; }
            else        { l = l + l2 * __expf(m2 - m); }
        }
        if ((tid & 63) == 0) { wm[tid >> 6] = m; wl[tid >> 6] = l; wa[tid >> 6] = am; }
        __syncthreads();
        if (tid == 0) {
            float M = wm[0], L = wl[0]; int A = wa[0];
#pragma unroll
            for (int wv = 1; wv < 4; ++wv) {
                float m2 = wm[wv], l2 = wl[wv]; int a2 = wa[wv];
                if (m2 > M) { L = L * __expf(M - m2) + l2; M = m2; A = a2; }
                else        { L += l2 * __expf(m2 - M); }
            }
            size_t o = (size_t)i * NCHUNK + chunk;
            pmP[o] = M; plP[o] = L; pamP[o] = A;
        }
    }
}

// ---------------------------------------------------------------------------
// Stage 2c-3: fold 32 chunk-partials per suspect -> final (scale, idx).
// ---------------------------------------------------------------------------
__global__ __launch_bounds__(256)
void recheck_fold(const float* __restrict__ pmP, const float* __restrict__ plP,
                  const int* __restrict__ pamP, const int* __restrict__ susp,
                  float* __restrict__ scl, int* __restrict__ sidx)
{
    int count = susp[0]; if (count > MAXSUSP) count = MAXSUSP;
    for (int i = blockIdx.x * 256 + threadIdx.x; i < count; i += gridDim.x * 256) {
        float M = -INFINITY, L = 0.f; int A = 0;
#pragma unroll
        for (int c = 0; c < NCHUNK; ++c) {
            size_t o = (size_t)i * NCHUNK + c;
            float m2 = pmP[o], l2 = plP[o]; int a2 = pamP[o];
            if (m2 > M) { L = L * __expf(M - m2) + l2; M = m2; A = a2; }
            else        { L += l2 * __expf(m2 - M); }
        }
        float p = 1.f / L;
        int row = susp[2 + i];
        scl[row] = (p >= THRESH) ? p : 0.f;
        sidx[row] = A;
    }
}

// ---------------------------------------------------------------------------
// Stage 3 v2: out[r] = scl[r] * (vh[idx[r]] @ Wp) + bp. Single-barrier:
// Wp half-tile DMA'd to LDS once; A-frags gathered per-lane from vh (fp16).
// ---------------------------------------------------------------------------
__global__ __launch_bounds__(256, 2)
void out_mfma(const _Float16* __restrict__ vh, const _Float16* __restrict__ Wph,
              const float* __restrict__ scl, const int* __restrict__ sidx,
              const float* __restrict__ bp, float* __restrict__ out)
{
    __shared__ half8 sB[4096];   // 64 KB Wp half-tile, grp = nt*8+ks
    int tid = threadIdx.x, w = tid >> 6, ln = tid & 63;
    int ln15 = ln & 15, ln4 = ln >> 4;
    int rb = blockIdx.x * 128, cbh = blockIdx.y;
    const _Float16* B = Wph + (size_t)cbh * 128 * DIM;

#pragma unroll
    for (int j = 0; j < 16; ++j) {
        int grp = w * 16 + j;
        int nt = grp >> 3, ks = grp & 7;
        const _Float16* src = B + (size_t)(nt * 16 + ln15) * DIM + ks * 32 + ln4 * 8;
        async_copy16(src, (char*)sB + grp * 1024);
    }

    half8 af[2][8];
#pragma unroll
    for (int mi = 0; mi < 2; ++mi) {
        int arow = rb + w * 32 + mi * 16 + ln15;
        const _Float16* ar = vh + (size_t)sidx[arow] * DIM + ln4 * 8;
#pragma unroll
        for (int ks = 0; ks < 8; ++ks)
            af[mi][ks] = *(const half8*)(ar + ks * 32);
    }

    __syncthreads();   // drains B DMA

    f32x4 acc[2][8];
#pragma unroll
    for (int mi = 0; mi < 2; ++mi)
#pragma unroll
        for (int nt = 0; nt < 8; ++nt) acc[mi][nt] = (f32x4){0.f, 0.f, 0.f, 0.f};

#pragma unroll
    for (int nt = 0; nt < 8; ++nt)
#pragma unroll
        for (int ks = 0; ks < 8; ++ks) {
            half8 bv = sB[(nt * 8 + ks) * 64 + ln];
            acc[0][nt] = __builtin_amdgcn_mfma_f32_16x16x32_f16(af[0][ks], bv, acc[0][nt], 0, 0, 0);
            acc[1][nt] = __builtin_amdgcn_mfma_f32_16x16x32_f16(af[1][ks], bv, acc[1][nt], 0, 0, 0);
        }

    int quad = ln4, cix = ln15;
#pragma unroll
    for (int mi = 0; mi < 2; ++mi)
#pragma unroll
        for (int rr = 0; rr < 4; ++rr) {
            int row = rb + (w * 2 + mi) * 16 + quad * 4 + rr;
            float sc = scl[row];
#pragma unroll
            for (int nt = 0; nt < 8; ++nt) {
                int col = cbh * 128 + nt * 16 + cix;
                out[(size_t)row * DIM + col] = acc[mi][nt][rr] * sc + bp[col];
            }
        }
}

// ---------------------------------------------------------------------------
extern "C" void kernel_launch(void* const* d_in, const int* in_sizes, int n_in,
                              void* d_out, int out_size, void* d_ws, size_t ws_size,
                              hipStream_t stream)
{
    (void)in_sizes; (void)n_in; (void)out_size; (void)ws_size;
    const float* x  = (const float*)d_in[0];
    const float* y  = (const float*)d_in[1];
    const float* Wq = (const float*)d_in[2];
    const float* Wk = (const float*)d_in[3];
    const float* Wv = (const float*)d_in[4];
    const float* Wp = (const float*)d_in[5];
    const float* bp = (const float*)d_in[6];
    float* out = (float*)d_out;

    // ws layout (~56 MB)
    float* p0 = (float*)d_ws;
    float* kf = p0;                 p0 += 4194304;
    float* Wt = p0;                 p0 += 65536;          // fp32 Wq^T (recheck)
    _Float16* Wth = (_Float16*)p0;  p0 += 4 * 65536 / 2;
    _Float16* qh  = (_Float16*)p0;  p0 += 2097152;
    _Float16* kh  = (_Float16*)p0;  p0 += 2097152;
    _Float16* vh  = (_Float16*)p0;  p0 += 2097152;
    float* pm  = p0;                p0 += 65536;
    float* pl  = p0;                p0 += 65536;
    int*  pam  = (int*)p0;          p0 += 65536;
    float* scl = p0;                p0 += 16384;
    int*  sidx = (int*)p0;          p0 += 16384;
    int*  susp = (int*)p0;          p0 += MAXSUSP + 2 + 2;
    float* qsusp = p0;              p0 += (size_t)MAXSUSP * DIM;
    float* pmP = p0;                p0 += (size_t)MAXSUSP * NCHUNK;
    float* plP = p0;                p0 += (size_t)MAXSUSP * NCHUNK;
    int*  pamP = (int*)p0;

    prep_kernel<<<64, 256, 0, stream>>>(Wq, Wk, Wv, Wp, Wt, Wth, susp);
    proj3_mfma<<<dim3(128, 2, 3), 256, 0, stream>>>(x, y, Wth, qh, kh, kf, vh);
    flash_fp16<<<dim3(16, 32), 256, 0, stream>>>(qh, kh, pm, pl, pam);
    merge_kernel<<<64, 256, 0, stream>>>(pm, pl, pam, scl, sidx, susp);
    recheck_q<<<128, 256, 0, stream>>>(x, Wt, susp, qsusp);
    recheck_part<<<dim3(NCHUNK, 64), 256, 0, stream>>>(qsusp, kf, susp, pmP, plP, pamP);
    recheck_fold<<<8, 256, 0, stream>>>(pmP, plP, pamP, susp, scl, sidx);
    out_mfma<<<dim3(128, 2), 256, 0, stream>>>(vh, Wth + 3 * 65536, scl, sidx, bp, out);
}

// Round 11
// 210.632 us; speedup vs baseline: 1.2760x; 1.0010x over previous
//
#include <hip/hip_runtime.h>
#include <cstdint>
#include <cmath>

#define DIM     256
#define NSEQ    4096
#define SCALE   0.17677669529663687f   // 32^-0.5
#define THRESH  0.6f
#define BAND    0.01f                  // recheck guard band
#define MAXSUSP 8000
#define NCHUNK  32                     // 4096 keys / 128
#define C1      0.2550349f             // SCALE * log2(e)
#define C2      28.8539008f            // 20 * log2(e)  (constant softmax shift)

using half8 = __attribute__((ext_vector_type(8))) _Float16;
using half4 = __attribute__((ext_vector_type(4))) _Float16;
using f32x4 = __attribute__((ext_vector_type(4))) float;

// async global->LDS DMA, 16 B per lane; ldst must be wave-uniform (HW adds lane*16)
__device__ __forceinline__ void async_copy16(const void* gsrc, void* ldst) {
    __builtin_amdgcn_global_load_lds(
        (const __attribute__((address_space(1))) void*)gsrc,
        (__attribute__((address_space(3))) void*)ldst, 16, 0, 0);
}

// fp32x8 -> half8 (A-fragment inline conversion)
__device__ __forceinline__ half8 cvt8(const float* p) {
    float4 f0 = *(const float4*)p;
    float4 f1 = *(const float4*)(p + 4);
    half8 hv;
    hv[0] = (_Float16)f0.x; hv[1] = (_Float16)f0.y; hv[2] = (_Float16)f0.z; hv[3] = (_Float16)f0.w;
    hv[4] = (_Float16)f1.x; hv[5] = (_Float16)f1.y; hv[6] = (_Float16)f1.z; hv[7] = (_Float16)f1.w;
    return hv;
}

// ---------------------------------------------------------------------------
// Prep: coalesced LDS-tiled transpose. Wth[m][c][k] = W_m[k][c] (fp16);
// Wt[c][k] = Wq[k][c] (fp32, recheck only). Zeroes susp.
// ---------------------------------------------------------------------------
__global__ void prep_kernel(const float* __restrict__ W0, const float* __restrict__ W1,
                            const float* __restrict__ W2, const float* __restrict__ W3,
                            float* __restrict__ Wt, _Float16* __restrict__ Wth,
                            int* __restrict__ susp)
{
    __shared__ float tile[64][68];
    int t = threadIdx.x;
    int m = blockIdx.x >> 4;
    int ti = blockIdx.x & 15;
    int tr = (ti >> 2) * 64, tc = (ti & 3) * 64;
    const float* W = (m == 0) ? W0 : (m == 1) ? W1 : (m == 2) ? W2 : W3;
    if (blockIdx.x == 0 && t < 2) susp[t] = 0;
    int rr = t >> 4, c4 = (t & 15) * 4;
#pragma unroll
    for (int p = 0; p < 4; ++p) {
        int row = p * 16 + rr;
        *(float4*)&tile[row][c4] = *(const float4*)(W + (size_t)(tr + row) * DIM + tc + c4);
    }
    __syncthreads();
#pragma unroll
    for (int p = 0; p < 4; ++p) {
        int c = p * 16 + rr;
        float4 v;
        v.x = tile[c4 + 0][c]; v.y = tile[c4 + 1][c];
        v.z = tile[c4 + 2][c]; v.w = tile[c4 + 3][c];
        size_t ot = (size_t)(tc + c) * DIM + tr + c4;
        if (m == 0) *(float4*)(Wt + ot) = v;
        half4 hv;
        hv[0] = (_Float16)v.x; hv[1] = (_Float16)v.y;
        hv[2] = (_Float16)v.z; hv[3] = (_Float16)v.w;
        *(half4*)(Wth + (size_t)m * 65536 + ot) = hv;
    }
}

// ---------------------------------------------------------------------------
// Stage 1 (A-reuse, kept from R10): block = 128 rows x ONE matrix (m=blockIdx.y).
// A frags in registers once; both 128-col W halves DMA'd + MFMA'd sequentially.
// ---------------------------------------------------------------------------
__global__ __launch_bounds__(256, 2)
void proj3_mfma(const float* __restrict__ x, const float* __restrict__ y,
                const _Float16* __restrict__ Wth,
                _Float16* __restrict__ qh, _Float16* __restrict__ kh,
                float* __restrict__ kf, _Float16* __restrict__ vh)
{
    __shared__ half8 sB[4096];   // 128 cols x 256 k fp16 = 64 KB, grp = nt*8+ks
    int tid = threadIdx.x, w = tid >> 6, ln = tid & 63;
    int ln15 = ln & 15, ln4 = ln >> 4;
    int rb = blockIdx.x * 128, m = blockIdx.y;
    const float* A = (m == 1) ? y : x;

    half8 af[2][8];
#pragma unroll
    for (int mi = 0; mi < 2; ++mi) {
        const float* ar = A + (size_t)(rb + w * 32 + mi * 16 + ln15) * DIM + ln4 * 8;
#pragma unroll
        for (int ks = 0; ks < 8; ++ks)
            af[mi][ks] = cvt8(ar + ks * 32);
    }

    for (int cbh = 0; cbh < 2; ++cbh) {
        if (cbh) __syncthreads();   // prior half's LDS reads complete
        const _Float16* B = Wth + (size_t)m * 65536 + (size_t)cbh * 128 * DIM;
#pragma unroll
        for (int j = 0; j < 16; ++j) {
            int grp = w * 16 + j;
            int nt = grp >> 3, ks = grp & 7;
            const _Float16* src = B + (size_t)(nt * 16 + ln15) * DIM + ks * 32 + ln4 * 8;
            async_copy16(src, (char*)sB + grp * 1024);
        }
        __syncthreads();   // drains B DMA

        f32x4 acc[2][8];
#pragma unroll
        for (int mi = 0; mi < 2; ++mi)
#pragma unroll
            for (int nt = 0; nt < 8; ++nt) acc[mi][nt] = (f32x4){0.f, 0.f, 0.f, 0.f};

#pragma unroll
        for (int nt = 0; nt < 8; ++nt)
#pragma unroll
            for (int ks = 0; ks < 8; ++ks) {
                half8 bv = sB[(nt * 8 + ks) * 64 + ln];
                acc[0][nt] = __builtin_amdgcn_mfma_f32_16x16x32_f16(af[0][ks], bv, acc[0][nt], 0, 0, 0);
                acc[1][nt] = __builtin_amdgcn_mfma_f32_16x16x32_f16(af[1][ks], bv, acc[1][nt], 0, 0, 0);
            }

#pragma unroll
        for (int mi = 0; mi < 2; ++mi)
#pragma unroll
            for (int nt = 0; nt < 8; ++nt)
#pragma unroll
                for (int rr = 0; rr < 4; ++rr) {
                    int row = rb + (w * 2 + mi) * 16 + ln4 * 4 + rr;
                    int col = cbh * 128 + nt * 16 + ln15;
                    size_t off = (size_t)row * DIM + col;
                    float vv = acc[mi][nt][rr];
                    if (m == 0)      qh[off] = (_Float16)vv;
                    else if (m == 1) { kh[off] = (_Float16)vv; kf[off] = vv; }
                    else             vh[off] = (_Float16)vv;
                }
    }
}

// ---------------------------------------------------------------------------
// Stage 2: R9-EXACT flash (known-good 49.4 us). R10's 32-key/ms8/lb4 variant
// FAILED correctness (absmax 2.2) — do not re-apply without isolation.
//  - 16 k-tiles of 64 keys; 2 x 32 KB buffers; one barrier/tile + prefetch
//  - qf[2][8] register A-frags; constant-shift softmax
// ---------------------------------------------------------------------------
__global__ __launch_bounds__(256, 2)
void flash_fp16(const _Float16* __restrict__ qh, const _Float16* __restrict__ kh,
                float* __restrict__ pm, float* __restrict__ pl, int* __restrict__ pam)
{
    __shared__ half8 sK[2][2048];   // 2 x (64 keys x 256 dims) = 2 x 32 KB
    int tid = threadIdx.x, w = tid >> 6, ln = tid & 63;
    int g = blockIdx.x;          // ms + 4*b
    int qt = blockIdx.y;
    int ms = g & 3, b = g >> 2;
    size_t qbase = (size_t)b * NSEQ + qt * 128 + w * 32;
    size_t krow0 = (size_t)b * NSEQ + ms * 1024;
    int ln15 = ln & 15, ln4 = ln >> 4;

    half8 qf[2][8];
#pragma unroll
    for (int mi = 0; mi < 2; ++mi) {
        const _Float16* qsrc = qh + (qbase + mi * 16 + ln15) * DIM + ln4 * 8;
#pragma unroll
        for (int ks = 0; ks < 8; ++ks)
            qf[mi][ks] = *(const half8*)(qsrc + ks * 32);
    }

    float rm[2][4], rl[2][4]; int ram[2][4];
#pragma unroll
    for (int mi = 0; mi < 2; ++mi)
#pragma unroll
        for (int rr = 0; rr < 4; ++rr) { rm[mi][rr] = -INFINITY; rl[mi][rr] = 0.f; ram[mi][rr] = 0; }

    // prologue: prefetch tile 0 into buffer 0 (32 groups of 1 KB; wave w: 8)
#pragma unroll
    for (int j = 0; j < 8; ++j) {
        int grp = w * 8 + j;
        const _Float16* src = kh + (krow0 + (grp >> 3) * 16 + ln15) * DIM + (grp & 7) * 32 + ln4 * 8;
        async_copy16(src, (char*)&sK[0][0] + grp * 1024);
    }

    for (int kt = 0; kt < 16; ++kt) {
        int cur = kt & 1;
        __syncthreads();   // tile kt's DMA complete; prior reads of buf[1-cur] done

        if (kt + 1 < 16) {
#pragma unroll
            for (int j = 0; j < 8; ++j) {
                int grp = w * 8 + j;
                const _Float16* src = kh + (krow0 + (kt + 1) * 64 + (grp >> 3) * 16 + ln15) * DIM
                                      + (grp & 7) * 32 + ln4 * 8;
                async_copy16(src, (char*)&sK[1 - cur][0] + grp * 1024);
            }
        }

        const half8* sKc = &sK[cur][0];
        f32x4 acc[2][4];
#pragma unroll
        for (int mi = 0; mi < 2; ++mi)
#pragma unroll
            for (int nt = 0; nt < 4; ++nt) acc[mi][nt] = (f32x4){0.f, 0.f, 0.f, 0.f};

#pragma unroll
        for (int nt = 0; nt < 4; ++nt)
#pragma unroll
            for (int ks = 0; ks < 8; ++ks) {
                half8 bk = sKc[(nt * 8 + ks) * 64 + ln];
                acc[0][nt] = __builtin_amdgcn_mfma_f32_16x16x32_f16(qf[0][ks], bk, acc[0][nt], 0, 0, 0);
                acc[1][nt] = __builtin_amdgcn_mfma_f32_16x16x32_f16(qf[1][ks], bk, acc[1][nt], 0, 0, 0);
            }

        int keybase = b * NSEQ + ms * 1024 + kt * 64 + ln15;
#pragma unroll
        for (int mi = 0; mi < 2; ++mi)
#pragma unroll
            for (int rr = 0; rr < 4; ++rr) {
                float mx = rm[mi][rr]; int amx = ram[mi][rr]; float ls = rl[mi][rr];
#pragma unroll
                for (int nt = 0; nt < 4; ++nt) {
                    float a = acc[mi][nt][rr];
                    ls += __builtin_amdgcn_exp2f(fmaf(a, C1, -C2));
                    if (a > mx) { mx = a; amx = keybase + nt * 16; }
                }
                rm[mi][rr] = mx; ram[mi][rr] = amx; rl[mi][rr] = ls;
            }
    }

    // fold the 16 key-lanes per row (xor<16 keeps quad = ln>>4): l adds, m/am max
#pragma unroll
    for (int mi = 0; mi < 2; ++mi)
#pragma unroll
        for (int rr = 0; rr < 4; ++rr) {
            float m0 = rm[mi][rr], l0 = rl[mi][rr]; int am0 = ram[mi][rr];
#pragma unroll
            for (int d = 1; d < 16; d <<= 1) {
                l0 += __shfl_xor(l0, d);
                float m2 = __shfl_xor(m0, d);
                int  am2 = __shfl_xor(am0, d);
                if (m2 > m0) { m0 = m2; am0 = am2; }
            }
            if (ln15 == 0) {
                int row = b * NSEQ + qt * 128 + w * 32 + mi * 16 + ln4 * 4 + rr;
                pm[row * 4 + ms] = m0; pl[row * 4 + ms] = l0; pam[row * 4 + ms] = am0;
            }
        }
}

// ---------------------------------------------------------------------------
// Stage 2b: merge 4 ms-split partials -> (scale, idx); flag near-boundary rows.
// pm holds raw-dot max; p = exp2(m*C1 - C2) / sum(l)  (shift cancels exactly).
// ---------------------------------------------------------------------------
__global__ void merge_kernel(const float* __restrict__ pm, const float* __restrict__ pl,
                             const int* __restrict__ pam,
                             float* __restrict__ scl, int* __restrict__ sidx,
                             int* __restrict__ susp)
{
    int row = blockIdx.x * 256 + threadIdx.x;
    float m = -INFINITY, l = 0.f; int am = 0;
#pragma unroll
    for (int s = 0; s < 4; ++s) {
        float m2 = pm[row * 4 + s];
        l += pl[row * 4 + s];
        if (m2 > m) { m = m2; am = pam[row * 4 + s]; }
    }
    float p = __builtin_amdgcn_exp2f(fmaf(m, C1, -C2)) / l;
    scl[row] = (p >= THRESH) ? p : 0.f;
    sidx[row] = am;
    if (fabsf(p - THRESH) < BAND) {
        int i = atomicAdd(susp, 1);
        if (i < MAXSUSP) susp[2 + i] = row;
    }
}

// ---------------------------------------------------------------------------
// Stage 2c-1: fp32 q-rows for suspects (Wq^T is L2-resident).
// ---------------------------------------------------------------------------
__global__ __launch_bounds__(256)
void recheck_q(const float* __restrict__ x, const float* __restrict__ Wtq,
               const int* __restrict__ susp, float* __restrict__ qsusp)
{
    int tid = threadIdx.x;
    int count = susp[0]; if (count > MAXSUSP) count = MAXSUSP;
    for (int i = blockIdx.x; i < count; i += gridDim.x) {
        int row = susp[2 + i];
        const float* xr = x + (size_t)row * DIM;
        const float* wr = Wtq + (size_t)tid * DIM;
        float a = 0.f;
        for (int d = 0; d < DIM; d += 4) {
            float4 xv = *(const float4*)(xr + d);
            float4 wv = *(const float4*)(wr + d);
            a = fmaf(xv.x, wv.x, a); a = fmaf(xv.y, wv.y, a);
            a = fmaf(xv.z, wv.z, a); a = fmaf(xv.w, wv.w, a);
        }
        qsusp[(size_t)i * DIM + tid] = a;
    }
}

// ---------------------------------------------------------------------------
// Stage 2c-2: key-parallel exact partials. Block = (chunk of 128 keys, suspect).
// ---------------------------------------------------------------------------
__global__ __launch_bounds__(256)
void recheck_part(const float* __restrict__ qsusp, const float* __restrict__ kf,
                  const int* __restrict__ susp,
                  float* __restrict__ pmP, float* __restrict__ plP, int* __restrict__ pamP)
{
    __shared__ float qs[DIM];
    __shared__ float wm[4], wl[4]; __shared__ int wa[4];
    int tid = threadIdx.x;
    int chunk = blockIdx.x;
    int count = susp[0]; if (count > MAXSUSP) count = MAXSUSP;

    for (int i = blockIdx.y; i < count; i += gridDim.y) {
        int row = susp[2 + i];
        int bb = row >> 12;
        __syncthreads();
        qs[tid] = qsusp[(size_t)i * DIM + tid];
        __syncthreads();

        int key = tid >> 1, h = tid & 1;
        int gkey = bb * NSEQ + chunk * 128 + key;
        const float* kr = kf + (size_t)gkey * DIM + h * 128;
        const float* qp = qs + h * 128;
        float dot = 0.f;
#pragma unroll
        for (int j = 0; j < 32; ++j) {
            float4 kv = *(const float4*)(kr + j * 4);
            float4 qv = *(const float4*)(qp + j * 4);
            dot = fmaf(qv.x, kv.x, dot); dot = fmaf(qv.y, kv.y, dot);
            dot = fmaf(qv.z, kv.z, dot); dot = fmaf(qv.w, kv.w, dot);
        }
        dot += __shfl_xor(dot, 1);
        float s = dot * SCALE;

        float m = (h == 0) ? s : -INFINITY;
        float l = (h == 0) ? 1.f : 0.f;
        int  am = (h == 0) ? gkey : 0;
#pragma unroll
        for (int d = 1; d < 64; d <<= 1) {
            float m2 = __shfl_xor(m, d);
            float l2 = __shfl_xor(l, d);
            int  a2 = __shfl_xor(am, d);
            if (m2 > m) { l = l * __expf(m - m2) + l2; m = m2; am = a2; }
            else        { l = l + l2 * __expf(m2 - m); }
        }
        if ((tid & 63) == 0) { wm[tid >> 6] = m; wl[tid >> 6] = l; wa[tid >> 6] = am; }
        __syncthreads();
        if (tid == 0) {
            float M = wm[0], L = wl[0]; int A = wa[0];
#pragma unroll
            for (int wv = 1; wv < 4; ++wv) {
                float m2 = wm[wv], l2 = wl[wv]; int a2 = wa[wv];
                if (m2 > M) { L = L * __expf(M - m2) + l2; M = m2; A = a2; }
                else        { L += l2 * __expf(m2 - M); }
            }
            size_t o = (size_t)i * NCHUNK + chunk;
            pmP[o] = M; plP[o] = L; pamP[o] = A;
        }
    }
}

// ---------------------------------------------------------------------------
// Stage 2c-3: fold 32 chunk-partials per suspect -> final (scale, idx).
// ---------------------------------------------------------------------------
__global__ __launch_bounds__(256)
void recheck_fold(const float* __restrict__ pmP, const float* __restrict__ plP,
                  const int* __restrict__ pamP, const int* __restrict__ susp,
                  float* __restrict__ scl, int* __restrict__ sidx)
{
    int count = susp[0]; if (count > MAXSUSP) count = MAXSUSP;
    for (int i = blockIdx.x * 256 + threadIdx.x; i < count; i += gridDim.x * 256) {
        float M = -INFINITY, L = 0.f; int A = 0;
#pragma unroll
        for (int c = 0; c < NCHUNK; ++c) {
            size_t o = (size_t)i * NCHUNK + c;
            float m2 = pmP[o], l2 = plP[o]; int a2 = pamP[o];
            if (m2 > M) { L = L * __expf(M - m2) + l2; M = m2; A = a2; }
            else        { L += l2 * __expf(m2 - M); }
        }
        float p = 1.f / L;
        int row = susp[2 + i];
        scl[row] = (p >= THRESH) ? p : 0.f;
        sidx[row] = A;
    }
}

// ---------------------------------------------------------------------------
// Stage 3 (A-reuse, kept from R10): vh gather once; both Wp halves looped.
// ---------------------------------------------------------------------------
__global__ __launch_bounds__(256, 2)
void out_mfma(const _Float16* __restrict__ vh, const _Float16* __restrict__ Wph,
              const float* __restrict__ scl, const int* __restrict__ sidx,
              const float* __restrict__ bp, float* __restrict__ out)
{
    __shared__ half8 sB[4096];   // 64 KB Wp half-tile, grp = nt*8+ks
    int tid = threadIdx.x, w = tid >> 6, ln = tid & 63;
    int ln15 = ln & 15, ln4 = ln >> 4;
    int rb = blockIdx.x * 128;

    half8 af[2][8];
#pragma unroll
    for (int mi = 0; mi < 2; ++mi) {
        int arow = rb + w * 32 + mi * 16 + ln15;
        const _Float16* ar = vh + (size_t)sidx[arow] * DIM + ln4 * 8;
#pragma unroll
        for (int ks = 0; ks < 8; ++ks)
            af[mi][ks] = *(const half8*)(ar + ks * 32);
    }

    for (int cbh = 0; cbh < 2; ++cbh) {
        if (cbh) __syncthreads();
        const _Float16* B = Wph + (size_t)cbh * 128 * DIM;
#pragma unroll
        for (int j = 0; j < 16; ++j) {
            int grp = w * 16 + j;
            int nt = grp >> 3, ks = grp & 7;
            const _Float16* src = B + (size_t)(nt * 16 + ln15) * DIM + ks * 32 + ln4 * 8;
            async_copy16(src, (char*)sB + grp * 1024);
        }
        __syncthreads();

        f32x4 acc[2][8];
#pragma unroll
        for (int mi = 0; mi < 2; ++mi)
#pragma unroll
            for (int nt = 0; nt < 8; ++nt) acc[mi][nt] = (f32x4){0.f, 0.f, 0.f, 0.f};

#pragma unroll
        for (int nt = 0; nt < 8; ++nt)
#pragma unroll
            for (int ks = 0; ks < 8; ++ks) {
                half8 bv = sB[(nt * 8 + ks) * 64 + ln];
                acc[0][nt] = __builtin_amdgcn_mfma_f32_16x16x32_f16(af[0][ks], bv, acc[0][nt], 0, 0, 0);
                acc[1][nt] = __builtin_amdgcn_mfma_f32_16x16x32_f16(af[1][ks], bv, acc[1][nt], 0, 0, 0);
            }

#pragma unroll
        for (int mi = 0; mi < 2; ++mi)
#pragma unroll
            for (int rr = 0; rr < 4; ++rr) {
                int row = rb + (w * 2 + mi) * 16 + ln4 * 4 + rr;
                float sc = scl[row];
#pragma unroll
                for (int nt = 0; nt < 8; ++nt) {
                    int col = cbh * 128 + nt * 16 + ln15;
                    out[(size_t)row * DIM + col] = acc[mi][nt][rr] * sc + bp[col];
                }
            }
    }
}

// ---------------------------------------------------------------------------
extern "C" void kernel_launch(void* const* d_in, const int* in_sizes, int n_in,
                              void* d_out, int out_size, void* d_ws, size_t ws_size,
                              hipStream_t stream)
{
    (void)in_sizes; (void)n_in; (void)out_size; (void)ws_size;
    const float* x  = (const float*)d_in[0];
    const float* y  = (const float*)d_in[1];
    const float* Wq = (const float*)d_in[2];
    const float* Wk = (const float*)d_in[3];
    const float* Wv = (const float*)d_in[4];
    const float* Wp = (const float*)d_in[5];
    const float* bp = (const float*)d_in[6];
    float* out = (float*)d_out;

    // ws layout (~55 MB) — R9 layout (pm/pl/pam stride 4)
    float* p0 = (float*)d_ws;
    float* kf = p0;                 p0 += 4194304;
    float* Wt = p0;                 p0 += 65536;          // fp32 Wq^T (recheck)
    _Float16* Wth = (_Float16*)p0;  p0 += 4 * 65536 / 2;
    _Float16* qh  = (_Float16*)p0;  p0 += 2097152;
    _Float16* kh  = (_Float16*)p0;  p0 += 2097152;
    _Float16* vh  = (_Float16*)p0;  p0 += 2097152;
    float* pm  = p0;                p0 += 65536;
    float* pl  = p0;                p0 += 65536;
    int*  pam  = (int*)p0;          p0 += 65536;
    float* scl = p0;                p0 += 16384;
    int*  sidx = (int*)p0;          p0 += 16384;
    int*  susp = (int*)p0;          p0 += MAXSUSP + 2 + 2;
    float* qsusp = p0;              p0 += (size_t)MAXSUSP * DIM;
    float* pmP = p0;                p0 += (size_t)MAXSUSP * NCHUNK;
    float* plP = p0;                p0 += (size_t)MAXSUSP * NCHUNK;
    int*  pamP = (int*)p0;

    prep_kernel<<<64, 256, 0, stream>>>(Wq, Wk, Wv, Wp, Wt, Wth, susp);
    proj3_mfma<<<dim3(128, 3), 256, 0, stream>>>(x, y, Wth, qh, kh, kf, vh);
    flash_fp16<<<dim3(16, 32), 256, 0, stream>>>(qh, kh, pm, pl, pam);
    merge_kernel<<<64, 256, 0, stream>>>(pm, pl, pam, scl, sidx, susp);
    recheck_q<<<128, 256, 0, stream>>>(x, Wt, susp, qsusp);
    recheck_part<<<dim3(NCHUNK, 64), 256, 0, stream>>>(qsusp, kf, susp, pmP, plP, pamP);
    recheck_fold<<<8, 256, 0, stream>>>(pmP, plP, pamP, susp, scl, sidx);
    out_mfma<<<128, 256, 0, stream>>>(vh, Wth + 3 * 65536, scl, sidx, bp, out);
}